// Round 14
// baseline (401.621 us; speedup 1.0000x reference)
//
#include <hip/hip_runtime.h>

#define NN 50000
#define NE 1600000
#define NFEAT 512
#define NHID 64
#define H1 8
#define NCLASS 16
#define ALPHA 0.2f

// bucketed CSR build: bucket = src >> 7 (128 nodes/bucket)
#define BUCKETS 391
#define CAP 6144              // staging slots per bucket
#define EPB 4096              // edges per pass-A block
#define PASSA_BLKS 391
#define PASSB_BLKS 391
#define PACK_BLKS 1024
#define PACK2_BLKS 32
#define GEMMB 391             // 391 row-blocks of 128, each does all 512 cols
#define NROW_PAD 50048        // 391*128

typedef __attribute__((ext_vector_type(8))) short short8;
typedef __attribute__((ext_vector_type(4))) float floatx4;
typedef __attribute__((ext_vector_type(2))) float floatx2;
typedef __attribute__((ext_vector_type(2))) long longx2;

__device__ __forceinline__ float elu_f(float x) { return x > 0.0f ? x : __expf(x) - 1.0f; }
__device__ __forceinline__ float edge_w(float logit) {
    return __expf(-fmaxf(logit, ALPHA * logit));   // exp(-leaky_relu)
}
__device__ __forceinline__ ushort f2bf(float f) {
    uint u = __float_as_uint(f);
    return (ushort)((u + 0x7FFFu + ((u >> 16) & 1)) >> 16);   // RNE
}
__device__ __forceinline__ uint packbf2(float lo, float hi) {
    return (uint)f2bf(lo) | ((uint)f2bf(hi) << 16);
}
__device__ __forceinline__ float bf2f(ushort v) { return __uint_as_float((uint)v << 16); }
__device__ __forceinline__ unsigned char f2fp8(float v) {
    return (unsigned char)(__builtin_amdgcn_cvt_pk_fp8_f32(v, v, 0, false) & 0xFF);
}
__device__ __forceinline__ uint pack4fp8(float a, float b, float c, float d) {
    uint u = __builtin_amdgcn_cvt_pk_fp8_f32(a, b, 0, false);
    return __builtin_amdgcn_cvt_pk_fp8_f32(c, d, u, true);
}

#define GLD16(g, l)                                                              \
    __builtin_amdgcn_global_load_lds(                                            \
        (const __attribute__((address_space(1))) unsigned int*)(g),              \
        (__attribute__((address_space(3))) unsigned int*)(l), 16, 0, 0)

// block-wide exclusive scan over 256 values (one per thread); *tot gets the sum.
__device__ __forceinline__ int scan256x(int v, int tid, int* wsum, int* tot) {
    int s = v;
#pragma unroll
    for (int o = 1; o < 64; o <<= 1) {
        int u = __shfl_up(s, o);
        if ((tid & 63) >= o) s += u;
    }
    __syncthreads();
    if ((tid & 63) == 63) wsum[tid >> 6] = s;
    __syncthreads();
    int off = 0, t = 0;
#pragma unroll
    for (int i = 0; i < 4; i++) {
        int x = wsum[i];
        if (i < (tid >> 6)) off += x;
        t += x;
    }
    *tot = t;
    return s - v + off;
}

// 512-thread variant (8 waves)
__device__ __forceinline__ int scan512x(int v, int tid, int* wsum, int* tot) {
    int s = v;
#pragma unroll
    for (int o = 1; o < 64; o <<= 1) {
        int u = __shfl_up(s, o);
        if ((tid & 63) >= o) s += u;
    }
    __syncthreads();
    if ((tid & 63) == 63) wsum[tid >> 6] = s;
    __syncthreads();
    int off = 0, t = 0;
#pragma unroll
    for (int i = 0; i < 8; i++) {
        int x = wsum[i];
        if (i < (tid >> 6)) off += x;
        t += x;
    }
    *tot = t;
    return s - v + off;
}

// ------- phase 0: pack W1 fp8 (swizzled) | pack W2^T bf16 | pass A bucket sort -------
__global__ __launch_bounds__(256) void prep_k(const float* __restrict__ W1,
                                              unsigned char* __restrict__ Wt8,
                                              const float* __restrict__ W2,
                                              ushort* __restrict__ W2tb,
                                              const int* __restrict__ ei,
                                              int* __restrict__ bucket_cnt,
                                              uint* __restrict__ staging) {
    int b = blockIdx.x;
    if (b < PACK_BLKS) {
        int i = b * 256 + threadIdx.x;   // OUTPUT index = c*512 + o
        int c = i >> 9, o = i & 511;
        int c6 = o >> 6, qhi = (o >> 4) & 3, kb = (o >> 3) & 1, bb = o & 7;
        int quad = qhi ^ ((c >> 1) & 3);
        int k = c6 * 64 + kb * 32 + quad * 8 + bb;
        Wt8[i] = f2fp8(W1[((c >> 6) * 512 + k) * 64 + (c & 63)]);
        return;
    }
    if (b < PACK_BLKS + PACK2_BLKS) {
        int i = (b - PACK_BLKS) * 256 + threadIdx.x;   // i = c*512 + f
        int c = i >> 9, f = i & 511;
        W2tb[i] = f2bf(W2[f * 16 + c]);
        return;
    }
    // ---- pass A: LDS counting-sort 4096 edges by bucket, write grouped runs ----
    __shared__ int histA[BUCKETS];
    __shared__ int exclA[BUCKETS];
    __shared__ int baseA[BUCKETS];
    __shared__ int wsumA[4];
    __shared__ uint ebuf[EPB];
    const int blk = b - PACK_BLKS - PACK2_BLKS;
    const int t = threadIdx.x;
    const int e0 = blk * EPB;
    const int cntb = min(EPB, NE - e0);
    for (int i = t; i < BUCKETS; i += 256) histA[i] = 0;
    __syncthreads();
    int br[16]; uint pay[16];
#pragma unroll
    for (int i = 0; i < 16; i++) {
        int e = e0 + i * 256 + t;
        br[i] = -1;
        if (e < NE) {
            int s = ei[e], d = ei[NE + e];
            int bu = s >> 7;
            pay[i] = ((uint)bu << 23) | ((uint)(s & 127) << 16) | (uint)d;  // 9b|7b|16b
            br[i] = (bu << 12) | atomicAdd(&histA[bu], 1);                  // rank < 4096
        }
    }
    __syncthreads();
    int tot0, tot1;
    int v0 = histA[t];
    int v1 = (t + 256 < BUCKETS) ? histA[t + 256] : 0;
    int p0 = scan256x(v0, t, wsumA, &tot0);
    int p1 = scan256x(v1, t, wsumA, &tot1);
    exclA[t] = p0;
    if (t + 256 < BUCKETS) exclA[t + 256] = p1 + tot0;
    __syncthreads();
    for (int i = t; i < BUCKETS; i += 256) {
        int c = histA[i];
        if (c > 0) baseA[i] = atomicAdd(&bucket_cnt[i], c);
    }
#pragma unroll
    for (int i = 0; i < 16; i++)
        if (br[i] >= 0) ebuf[exclA[br[i] >> 12] + (br[i] & 4095)] = pay[i];
    __syncthreads();
    for (int j = t; j < cntb; j += 256) {
        uint v = ebuf[j];
        int bu = v >> 23;
        int pos = baseA[bu] + (j - exclA[bu]);
        staging[(size_t)bu * CAP + pos] = v;
    }
}

// ===== pass B standalone: padded local CSR build (391 blocks x 512) =====
__global__ __launch_bounds__(512) void passb_k(const int* __restrict__ bucket_cnt,
                                               const uint* __restrict__ staging,
                                               ushort* __restrict__ csru,
                                               int* __restrict__ rowptr) {
    __shared__ int hist2w[1024];   // [8][128] per-wave histogram
    __shared__ int cur2w[1024];    // [8][128] per-wave cursor
    __shared__ int wbase[1024];    // [8][128] per-wave base within node segment
    __shared__ int excl2[128];     // per-node exclusive scan
    __shared__ int wsum2[8];
    __shared__ int sbs;
    const int tid = threadIdx.x;
    const int b = blockIdx.x;
    const int cnt = bucket_cnt[b];
    const uint* sg = staging + (size_t)b * CAP;
    const int wv = tid >> 6;
    for (int i = tid; i < 2048; i += 512) {
        if (i < 1024) hist2w[i] = 0; else cur2w[i - 1024] = 0;
    }
    // wave 0: exclusive prefix of bucket_cnt up to bucket b (391 L2-hit reads)
    if (tid < 64) {
        int c[7]; int s0 = 0;
#pragma unroll
        for (int i = 0; i < 7; i++) {
            int bi = tid * 7 + i;
            c[i] = (bi < BUCKETS) ? bucket_cnt[bi] : 0;
            s0 += c[i];
        }
        int sc = s0;
#pragma unroll
        for (int o = 1; o < 64; o <<= 1) {
            int u = __shfl_up(sc, o);
            if (tid >= o) sc += u;
        }
        int run = sc - s0;   // exclusive prefix at this lane's first bucket
        if (tid == b / 7) {
            int part = run;
            for (int i = 0; i < b % 7; i++) part += c[i];
            sbs = part;
        }
    }
    if (b == 0 && tid == 0) rowptr[NN] = NE;
    __syncthreads();
    const int sbase = sbs;
    for (int e = tid; e < cnt; e += 512)
        atomicAdd(&hist2w[wv * 128 + ((sg[e] >> 16) & 127)], 1);
    __syncthreads();
    int v = 0;
    if (tid < 128) {
        int run = 0;
#pragma unroll
        for (int w = 0; w < 8; w++) {
            wbase[w * 128 + tid] = run;
            run += hist2w[w * 128 + tid];
        }
        v = run;                     // node total
    }
    int tot;
    int ex = scan512x(v, tid, wsum2, &tot);
    if (tid < 128) {
        excl2[tid] = ex;
        int n = b * 128 + tid;
        if (n < NN) rowptr[n] = sbase + ex;
    }
    __syncthreads();
    for (int e = tid; e < cnt; e += 512) {
        uint u = sg[e];
        int sl = (u >> 16) & 127;
        int pos = excl2[sl] + wbase[wv * 128 + sl] + atomicAdd(&cur2w[wv * 128 + sl], 1);
        csru[sbase + pos] = (ushort)(u & 0xFFFF);
    }
}

// ===== GEMM1 standalone: fp8 MFMA, 128 rows x 512 cols per block (391 x 512thr) =====
// A-path: direct fp32 loads from x into regs + in-reg fp8 convert.
// B-path: GLD16 -> LDS (pre-swizzled Wt8).
__global__ __launch_bounds__(512) void gemm1_k(const float* __restrict__ x,
                                               const unsigned char* __restrict__ Wt8,
                                               const float* __restrict__ a1,
                                               unsigned char* __restrict__ h8,
                                               float* __restrict__ s1s,
                                               float* __restrict__ s1d) {
    __shared__ unsigned char Bs[32768];     // 512 x 64
    const int tid = threadIdx.x;
    const int gb = blockIdx.x;
    const int row0 = gb * 128;
    const int wv = tid >> 6, lane = tid & 63;
    const int l16 = lane & 15, quad = lane >> 4;
    const int qoff = ((quad ^ ((l16 >> 1) & 3)) << 4);   // swizzled 16-B slot (B reads)
    const int mA = wv * 16 + (lane >> 2);
    const int offA = (lane & 3) * 16;
    const unsigned char* gB0 = Wt8 + (size_t)(0 * 128 + mA) * 512 + offA;
    const unsigned char* gB1 = Wt8 + (size_t)(1 * 128 + mA) * 512 + offA;
    const unsigned char* gB2 = Wt8 + (size_t)(2 * 128 + mA) * 512 + offA;
    const unsigned char* gB3 = Wt8 + (size_t)(3 * 128 + mA) * 512 + offA;
    const int arow = row0 + wv * 16 + l16;               // this lane's A row
    const int arowc = min(arow, NN - 1);                 // clamp (pad rows discarded)
    const float* xA = x + (size_t)arowc * 512 + quad * 8;

    floatx4 acc[32];
#pragma unroll
    for (int ct = 0; ct < 32; ct++) acc[ct] = (floatx4){0.f, 0.f, 0.f, 0.f};

    for (int t = 0; t < 8; t++) {
        const int k0 = t * 64;
        GLD16(gB0 + k0, Bs + wv * 1024);
        GLD16(gB1 + k0, Bs + 8192 + wv * 1024);
        GLD16(gB2 + k0, Bs + 16384 + wv * 1024);
        GLD16(gB3 + k0, Bs + 24576 + wv * 1024);
        // A fragment: k = k0 + quad*8 + b (kb=0) and k0 + 32 + quad*8 + b (kb=1)
        float4 f0 = *(const float4*)(xA + k0);
        float4 f1 = *(const float4*)(xA + k0 + 4);
        float4 f2 = *(const float4*)(xA + k0 + 32);
        float4 f3 = *(const float4*)(xA + k0 + 36);
        uint u0 = pack4fp8(f0.x, f0.y, f0.z, f0.w);
        uint u1 = pack4fp8(f1.x, f1.y, f1.z, f1.w);
        uint u2 = pack4fp8(f2.x, f2.y, f2.z, f2.w);
        uint u3 = pack4fp8(f3.x, f3.y, f3.z, f3.w);
        long ax = (long)(((unsigned long)u1 << 32) | u0);
        long ay = (long)(((unsigned long)u3 << 32) | u2);
        __syncthreads();                 // B tile visible (drains GLD16 too)
        const unsigned char* bp = Bs + l16 * 64 + qoff;
#pragma unroll
        for (int ct = 0; ct < 32; ct++) {
            longx2 bv = *(const longx2*)(bp + ct * 1024);
            acc[ct] = __builtin_amdgcn_mfma_f32_16x16x32_fp8_fp8(ax, bv.x, acc[ct], 0, 0, 0);
            acc[ct] = __builtin_amdgcn_mfma_f32_16x16x32_fp8_fp8(ay, bv.y, acc[ct], 0, 0, 0);
        }
        __syncthreads();                 // all reads done before next-tile overwrite
    }

    // epilogue: h8 write + a1 scores
    const int rbase = row0 + wv * 16 + quad * 4;
#pragma unroll
    for (int hh = 0; hh < 8; hh++) {
        float ss[4] = {0.f, 0.f, 0.f, 0.f}, sd[4] = {0.f, 0.f, 0.f, 0.f};
#pragma unroll
        for (int c4 = 0; c4 < 4; c4++) {
            int ct = hh * 4 + c4;
            int colg = ct * 16 + l16;
            float avs = a1[hh * 128 + c4 * 16 + l16];
            float avd = a1[hh * 128 + 64 + c4 * 16 + l16];
#pragma unroll
            for (int r = 0; r < 4; r++) {
                float v = acc[ct][r];
                ss[r] += v * avs;
                sd[r] += v * avd;
                int row = rbase + r;
                if (row < NN) h8[(size_t)row * 512 + colg] = f2fp8(v);
            }
        }
#pragma unroll
        for (int r = 0; r < 4; r++) {
            float a_ = ss[r], b_ = sd[r];
#pragma unroll
            for (int o = 1; o < 16; o <<= 1) {
                a_ += __shfl_xor(a_, o);
                b_ += __shfl_xor(b_, o);
            }
            int row = rbase + r;
            if (l16 == 0 && row < NN) {
                s1s[row * 8 + hh] = a_;
                s1d[row * 8 + hh] = b_;
            }
        }
    }
}

// ===== fused layer-1 aggregation (fp8 gather, one-ahead index prefetch) + GEMM2 + scores =====
// n_base: launched twice over half the node range each (attribution; halves independent).
__global__ __launch_bounds__(256) void agg1f_k(const int n_base,
                                               const int* __restrict__ rowptr,
                                               const ushort* __restrict__ csru,
                                               const float* __restrict__ s1s,
                                               const float* __restrict__ s1d,
                                               const uint2* __restrict__ hb8,
                                               const ushort* __restrict__ W2tb,
                                               const float* __restrict__ a2,
                                               ushort* __restrict__ h2b,
                                               float* __restrict__ s2s,
                                               float* __restrict__ s2d) {
    __shared__ ushort Ash[16 * 512];
    unsigned char* ashb = (unsigned char*)Ash;
    const int tid = threadIdx.x;
    const int wv = tid >> 6, lane = tid & 63;
    const int n0 = n_base + blockIdx.x * 4;
    const int n = n0 + wv;              // NN % 4 == 0
    const int head8 = lane >> 3;
    const int hb = head8 << 3;
    const int esub = lane & 7;
    const int beg = rowptr[n];
    const int deg = rowptr[n + 1] - beg;
    const float ssrc = s1s[n * 8 + head8];
    floatx2 acc[4] = {};
    float rsum = 0.f;

    const int G = (deg + 7) >> 3;       // clamped groups; last group zero-weights invalid lanes
    const int dm1 = deg - 1;
    if (G > 0) {
        int dA = csru[beg + min(esub, dm1)];
        float tw = s1d[dA * 8 + head8];
        for (int g = 0; g < G; g++) {
            // gathers for the CURRENT group issue immediately (dA already in regs)
            uint2 v[8];
#pragma unroll
            for (int j = 0; j < 8; j++) {
                int dj = __shfl(dA, j);
                v[j] = hb8[(uint)dj * 64 + lane];
            }
            // one-ahead prefetch of next group's index + dst-score (clamped, ~4 VGPRs)
            int dAn = csru[beg + min(g * 8 + 8 + esub, dm1)];
            float twn = s1d[dAn * 8 + head8];
            float w = (g * 8 + esub <= dm1) ? edge_w(ssrc + tw) : 0.f;
            rsum += w;
#pragma unroll
            for (int j = 0; j < 8; j++) {
                float wj = __shfl(w, hb + j);
                floatx2 w2 = (floatx2){wj, wj};
                acc[0] += w2 * __builtin_amdgcn_cvt_pk_f32_fp8(v[j].x, false);
                acc[1] += w2 * __builtin_amdgcn_cvt_pk_f32_fp8(v[j].x, true);
                acc[2] += w2 * __builtin_amdgcn_cvt_pk_f32_fp8(v[j].y, false);
                acc[3] += w2 * __builtin_amdgcn_cvt_pk_f32_fp8(v[j].y, true);
            }
            dA = dAn;
            tw = twn;
        }
    }

    rsum += __shfl_xor(rsum, 1);
    rsum += __shfl_xor(rsum, 2);
    rsum += __shfl_xor(rsum, 4);
    float inv = 1.0f / rsum;
    uint4 o;
    o.x = packbf2(elu_f(acc[0][0] * inv), elu_f(acc[0][1] * inv));
    o.y = packbf2(elu_f(acc[1][0] * inv), elu_f(acc[1][1] * inv));
    o.z = packbf2(elu_f(acc[2][0] * inv), elu_f(acc[2][1] * inv));
    o.w = packbf2(elu_f(acc[3][0] * inv), elu_f(acc[3][1] * inv));
    // XOR-swizzled store: col16 ^ (row<<4) breaks stride-1024 bank aliasing for GEMM2 reads
    *(uint4*)(ashb + wv * 1024 + ((lane * 16) ^ (wv << 4))) = o;
    __syncthreads();

    if (wv == 0) {
        const int l16 = lane & 15, q = lane >> 4;
        floatx4 c2 = (floatx4){0.f, 0.f, 0.f, 0.f};
#pragma unroll
        for (int s = 0; s < 16; s++) {
            short8 af = *(const short8*)(ashb + l16 * 1024 +
                                         ((s * 64 + q * 16) ^ ((l16 & 7) << 4)));
            short8 bf = *(const short8*)(W2tb + l16 * 512 + s * 32 + q * 8);
            c2 = __builtin_amdgcn_mfma_f32_16x16x32_bf16(af, bf, c2, 0, 0, 0);
        }
        if (q == 0) {
#pragma unroll
            for (int r = 0; r < 4; r++) h2b[(size_t)(n0 + r) * 16 + l16] = f2bf(c2[r]);
        }
#pragma unroll
        for (int r = 0; r < 4; r++) {
            float ssv = c2[r] * a2[l16];
            float sdv = c2[r] * a2[16 + l16];
#pragma unroll
            for (int oo = 1; oo < 16; oo <<= 1) {
                ssv += __shfl_xor(ssv, oo);
                sdv += __shfl_xor(sdv, oo);
            }
            if (lane == 0) { s2s[n0 + r] = ssv; s2d[n0 + r] = sdv; }
        }
    }
}

// ===== layer-2 aggregation (bf16 h2, 4-deep) + fused log_softmax =====
__global__ __launch_bounds__(256) void agg2_k(const int* __restrict__ rowptr,
                                              const ushort* __restrict__ csru,
                                              const float* __restrict__ s2s,
                                              const float* __restrict__ s2d,
                                              const ushort* __restrict__ h2b,
                                              float* __restrict__ out) {
    const int n = (blockIdx.x * 256 + threadIdx.x) >> 6;
    const int lane = threadIdx.x & 63;
    if (n >= NN) return;
    const int beg = rowptr[n], end = rowptr[n + 1];
    const float sn = s2s[n];
    const int sub = lane >> 4, f = lane & 15;
    float acc = 0.f, rsum = 0.f;
    int e = beg + sub;
    for (; e + 12 < end; e += 16) {          // 4 edges in flight per subgroup
        int d0 = csru[e], d1 = csru[e + 4], d2 = csru[e + 8], d3 = csru[e + 12];
        float t0 = s2d[d0], t1 = s2d[d1], t2 = s2d[d2], t3 = s2d[d3];
        float g0 = bf2f(h2b[(uint)d0 * 16 + f]), g1 = bf2f(h2b[(uint)d1 * 16 + f]);
        float g2 = bf2f(h2b[(uint)d2 * 16 + f]), g3 = bf2f(h2b[(uint)d3 * 16 + f]);
        float w0 = edge_w(sn + t0), w1 = edge_w(sn + t1);
        float w2 = edge_w(sn + t2), w3 = edge_w(sn + t3);
        acc += w0 * g0 + w1 * g1 + w2 * g2 + w3 * g3;
        rsum += w0 + w1 + w2 + w3;
    }
    for (; e < end; e += 4) {
        int d0 = csru[e];
        float w0 = edge_w(sn + s2d[d0]);
        acc += w0 * bf2f(h2b[(uint)d0 * 16 + f]);
        rsum += w0;
    }
    acc += __shfl_down(acc, 32);
    acc += __shfl_down(acc, 16);
    rsum += __shfl_down(rsum, 32);
    rsum += __shfl_down(rsum, 16);
    if (lane < 16) {
        float v = elu_f(acc / rsum);
        float m = v;
#pragma unroll
        for (int o = 8; o > 0; o >>= 1) m = fmaxf(m, __shfl_xor(m, o));
        float ex = __expf(v - m), s = ex;
#pragma unroll
        for (int o = 8; o > 0; o >>= 1) s += __shfl_xor(s, o);
        out[(size_t)n * 16 + f] = v - (__logf(s) + m);
    }
}

extern "C" void kernel_launch(void* const* d_in, const int* in_sizes, int n_in,
                              void* d_out, int out_size, void* d_ws, size_t ws_size,
                              hipStream_t stream) {
    const float* x  = (const float*)d_in[0];
    const int*   ei = (const int*)d_in[1];
    const float* W1 = (const float*)d_in[2];
    const float* a1 = (const float*)d_in[3];
    const float* W2 = (const float*)d_in[4];
    const float* a2 = (const float*)d_in[5];
    float* out = (float*)d_out;

    unsigned char* h8  = (unsigned char*)d_ws;              // 50048*512 = 25.62 MB
    unsigned char* Wt8 = h8 + (size_t)NROW_PAD * 512;       // 256 KB
    ushort* W2tb  = (ushort*)(Wt8 + 512 * 512);             // 16 KB
    float* s1s    = (float*)(W2tb + 8192);                  // 1.6 MB
    float* s1d    = s1s + (size_t)NN * H1;                  // 1.6 MB
    int* rowptr   = (int*)(s1d + (size_t)NN * H1);          // NN+1 (padded to 50056)
    int* bucket_cnt   = rowptr + 50056;                     // 512 ints
    int* bucket_start = bucket_cnt + 512;                   // 512 ints (unused, kept for layout)
    ushort* csru  = (ushort*)(bucket_start + 512);          // 3.2 MB
    ushort* h2b   = csru + NE;                              // 1.6 MB
    float* s2s    = (float*)(h2b + (size_t)NN * 16);        // 200 KB
    float* s2d    = s2s + NN;                               // 200 KB
    uint* staging = (uint*)(s2d + NN);                      // 391*6144*4 = 9.6 MB

    hipMemsetAsync(bucket_cnt, 0, 512 * sizeof(int), stream);

    prep_k<<<PACK_BLKS + PACK2_BLKS + PASSA_BLKS, 256, 0, stream>>>(
        W1, Wt8, W2, W2tb, ei, bucket_cnt, staging);
    passb_k<<<PASSB_BLKS, 512, 0, stream>>>(bucket_cnt, staging, csru, rowptr);
    gemm1_k<<<GEMMB, 512, 0, stream>>>(x, Wt8, a1, h8, s1s, s1d);
    agg1f_k<<<NN / 8, 256, 0, stream>>>(0, rowptr, csru, s1s, s1d,
                                        (const uint2*)h8, W2tb, a2, h2b, s2s, s2d);
    agg1f_k<<<NN / 8, 256, 0, stream>>>(NN / 2, rowptr, csru, s1s, s1d,
                                        (const uint2*)h8, W2tb, a2, h2b, s2s, s2d);
    agg2_k<<<(NN + 3) / 4, 256, 0, stream>>>(rowptr, csru, s2s, s2d, h2b, out);
}

// Round 15
// 397.987 us; speedup vs baseline: 1.0091x; 1.0091x over previous
//
#include <hip/hip_runtime.h>

#define NN 50000
#define NE 1600000
#define NFEAT 512
#define NHID 64
#define H1 8
#define NCLASS 16
#define ALPHA 0.2f

// bucketed CSR build: bucket = src >> 7 (128 nodes/bucket)
#define BUCKETS 391
#define CAP 6144              // staging slots per bucket
#define EPB 4096              // edges per pass-A block
#define PASSA_BLKS 391
#define PASSB_BLKS 391
#define PACK_BLKS 1024
#define PACK2_BLKS 32
#define GEMMB 391             // 391 row-blocks of 128, each does all 512 cols
#define NROW_PAD 50048        // 391*128

typedef __attribute__((ext_vector_type(8))) short short8;
typedef __attribute__((ext_vector_type(4))) float floatx4;
typedef __attribute__((ext_vector_type(2))) float floatx2;
typedef __attribute__((ext_vector_type(2))) long longx2;

__device__ __forceinline__ float elu_f(float x) { return x > 0.0f ? x : __expf(x) - 1.0f; }
__device__ __forceinline__ float edge_w(float logit) {
    return __expf(-fmaxf(logit, ALPHA * logit));   // exp(-leaky_relu)
}
__device__ __forceinline__ ushort f2bf(float f) {
    uint u = __float_as_uint(f);
    return (ushort)((u + 0x7FFFu + ((u >> 16) & 1)) >> 16);   // RNE
}
__device__ __forceinline__ uint packbf2(float lo, float hi) {
    return (uint)f2bf(lo) | ((uint)f2bf(hi) << 16);
}
__device__ __forceinline__ float bf2f(ushort v) { return __uint_as_float((uint)v << 16); }
__device__ __forceinline__ unsigned char f2fp8(float v) {
    return (unsigned char)(__builtin_amdgcn_cvt_pk_fp8_f32(v, v, 0, false) & 0xFF);
}
__device__ __forceinline__ uint pack4fp8(float a, float b, float c, float d) {
    uint u = __builtin_amdgcn_cvt_pk_fp8_f32(a, b, 0, false);
    return __builtin_amdgcn_cvt_pk_fp8_f32(c, d, u, true);
}

#define GLD16(g, l)                                                              \
    __builtin_amdgcn_global_load_lds(                                            \
        (const __attribute__((address_space(1))) unsigned int*)(g),              \
        (__attribute__((address_space(3))) unsigned int*)(l), 16, 0, 0)

// 512-thread block-wide exclusive scan (one value per thread); *tot gets the sum.
__device__ __forceinline__ int scan512x(int v, int tid, int* wsum, int* tot) {
    int s = v;
#pragma unroll
    for (int o = 1; o < 64; o <<= 1) {
        int u = __shfl_up(s, o);
        if ((tid & 63) >= o) s += u;
    }
    __syncthreads();
    if ((tid & 63) == 63) wsum[tid >> 6] = s;
    __syncthreads();
    int off = 0, t = 0;
#pragma unroll
    for (int i = 0; i < 8; i++) {
        int x = wsum[i];
        if (i < (tid >> 6)) off += x;
        t += x;
    }
    *tot = t;
    return s - v + off;
}

// ------- phase 0: pack W1 fp8 (swizzled) | pack W2^T bf16 (small, serial) -------
__global__ __launch_bounds__(256) void prep_w_k(const float* __restrict__ W1,
                                                unsigned char* __restrict__ Wt8,
                                                const float* __restrict__ W2,
                                                ushort* __restrict__ W2tb) {
    int b = blockIdx.x;
    if (b < PACK_BLKS) {
        int i = b * 256 + threadIdx.x;   // OUTPUT index = c*512 + o
        int c = i >> 9, o = i & 511;
        int c6 = o >> 6, qhi = (o >> 4) & 3, kb = (o >> 3) & 1, bb = o & 7;
        int quad = qhi ^ ((c >> 1) & 3);
        int k = c6 * 64 + kb * 32 + quad * 8 + bb;
        Wt8[i] = f2fp8(W1[((c >> 6) * 512 + k) * 64 + (c & 63)]);
        return;
    }
    int i = (b - PACK_BLKS) * 256 + threadIdx.x;   // i = c*512 + f
    int c = i >> 9, f = i & 511;
    W2tb[i] = f2bf(W2[f * 16 + c]);
}

// ===== merged: pass A bucket sort (blocks 0..390) | GEMM1 fp8 MFMA (blocks 391..781) =====
// pass A has no dependency on the GEMM; its blocks co-reside with the latency-bound GEMM
// blocks and hide under them (R11-measured mechanism: pass-B merged cost only +8.6us).
__global__ __launch_bounds__(512) void passa_gemm1_k(const int* __restrict__ ei,
                                                     int* __restrict__ bucket_cnt,
                                                     uint* __restrict__ staging,
                                                     const float* __restrict__ x,
                                                     const unsigned char* __restrict__ Wt8,
                                                     const float* __restrict__ a1,
                                                     unsigned char* __restrict__ h8,
                                                     float* __restrict__ s1s,
                                                     float* __restrict__ s1d) {
    __shared__ unsigned char shmem[32768];   // GEMM: Bs 32 KB; pass-A: ~21 KB arrays
    const int tid = threadIdx.x;

    if (blockIdx.x < PASSA_BLKS) {
        // ---- pass A (512 threads): LDS counting-sort 4096 edges by bucket ----
        int* histA = (int*)shmem;            // 391 (padded 400)
        int* exclA = histA + 400;            // 391
        int* baseA = exclA + 400;            // 391
        int* wsumA = baseA + 400;            // 8
        uint* ebuf = (uint*)(wsumA + 8);     // 4096
        const int blk = blockIdx.x;
        const int e0 = blk * EPB;
        const int cntb = min(EPB, NE - e0);
        for (int i = tid; i < BUCKETS; i += 512) histA[i] = 0;
        __syncthreads();
        int br[8]; uint pay[8];
#pragma unroll
        for (int i = 0; i < 8; i++) {
            int e = e0 + i * 512 + tid;
            br[i] = -1;
            if (e < NE) {
                int s = ei[e], d = ei[NE + e];
                int bu = s >> 7;
                pay[i] = ((uint)bu << 23) | ((uint)(s & 127) << 16) | (uint)d;  // 9b|7b|16b
                br[i] = (bu << 12) | atomicAdd(&histA[bu], 1);                  // rank < 4096
            }
        }
        __syncthreads();
        int v = (tid < BUCKETS) ? histA[tid] : 0;
        int tot;
        int ex = scan512x(v, tid, wsumA, &tot);
        if (tid < BUCKETS) exclA[tid] = ex;
        __syncthreads();
        for (int i = tid; i < BUCKETS; i += 512) {
            int c = histA[i];
            if (c > 0) baseA[i] = atomicAdd(&bucket_cnt[i], c);
        }
#pragma unroll
        for (int i = 0; i < 8; i++)
            if (br[i] >= 0) ebuf[exclA[br[i] >> 12] + (br[i] & 4095)] = pay[i];
        __syncthreads();
        for (int j = tid; j < cntb; j += 512) {
            uint u = ebuf[j];
            int bu = u >> 23;
            int pos = baseA[bu] + (j - exclA[bu]);
            staging[(size_t)bu * CAP + pos] = u;
        }
        return;
    }

    // ------------------ GEMM1 (unchanged from R14) ------------------
    unsigned char* Bs = shmem;              // 512 x 64 = 32 KB
    const int gb = blockIdx.x - PASSA_BLKS;
    const int row0 = gb * 128;
    const int wv = tid >> 6, lane = tid & 63;
    const int l16 = lane & 15, quad = lane >> 4;
    const int qoff = ((quad ^ ((l16 >> 1) & 3)) << 4);   // swizzled 16-B slot (B reads)
    const int mA = wv * 16 + (lane >> 2);
    const int offA = (lane & 3) * 16;
    const unsigned char* gB0 = Wt8 + (size_t)(0 * 128 + mA) * 512 + offA;
    const unsigned char* gB1 = Wt8 + (size_t)(1 * 128 + mA) * 512 + offA;
    const unsigned char* gB2 = Wt8 + (size_t)(2 * 128 + mA) * 512 + offA;
    const unsigned char* gB3 = Wt8 + (size_t)(3 * 128 + mA) * 512 + offA;
    const int arow = row0 + wv * 16 + l16;               // this lane's A row
    const int arowc = min(arow, NN - 1);                 // clamp (pad rows discarded)
    const float* xA = x + (size_t)arowc * 512 + quad * 8;

    floatx4 acc[32];
#pragma unroll
    for (int ct = 0; ct < 32; ct++) acc[ct] = (floatx4){0.f, 0.f, 0.f, 0.f};

    for (int t = 0; t < 8; t++) {
        const int k0 = t * 64;
        GLD16(gB0 + k0, Bs + wv * 1024);
        GLD16(gB1 + k0, Bs + 8192 + wv * 1024);
        GLD16(gB2 + k0, Bs + 16384 + wv * 1024);
        GLD16(gB3 + k0, Bs + 24576 + wv * 1024);
        // A fragment: k = k0 + quad*8 + b (kb=0) and k0 + 32 + quad*8 + b (kb=1)
        float4 f0 = *(const float4*)(xA + k0);
        float4 f1 = *(const float4*)(xA + k0 + 4);
        float4 f2 = *(const float4*)(xA + k0 + 32);
        float4 f3 = *(const float4*)(xA + k0 + 36);
        uint u0 = pack4fp8(f0.x, f0.y, f0.z, f0.w);
        uint u1 = pack4fp8(f1.x, f1.y, f1.z, f1.w);
        uint u2 = pack4fp8(f2.x, f2.y, f2.z, f2.w);
        uint u3 = pack4fp8(f3.x, f3.y, f3.z, f3.w);
        long ax = (long)(((unsigned long)u1 << 32) | u0);
        long ay = (long)(((unsigned long)u3 << 32) | u2);
        __syncthreads();                 // B tile visible (drains GLD16 too)
        const unsigned char* bp = Bs + l16 * 64 + qoff;
#pragma unroll
        for (int ct = 0; ct < 32; ct++) {
            longx2 bv = *(const longx2*)(bp + ct * 1024);
            acc[ct] = __builtin_amdgcn_mfma_f32_16x16x32_fp8_fp8(ax, bv.x, acc[ct], 0, 0, 0);
            acc[ct] = __builtin_amdgcn_mfma_f32_16x16x32_fp8_fp8(ay, bv.y, acc[ct], 0, 0, 0);
        }
        __syncthreads();                 // all reads done before next-tile overwrite
    }

    // epilogue: h8 write + a1 scores
    const int rbase = row0 + wv * 16 + quad * 4;
#pragma unroll
    for (int hh = 0; hh < 8; hh++) {
        float ss[4] = {0.f, 0.f, 0.f, 0.f}, sd[4] = {0.f, 0.f, 0.f, 0.f};
#pragma unroll
        for (int c4 = 0; c4 < 4; c4++) {
            int ct = hh * 4 + c4;
            int colg = ct * 16 + l16;
            float avs = a1[hh * 128 + c4 * 16 + l16];
            float avd = a1[hh * 128 + 64 + c4 * 16 + l16];
#pragma unroll
            for (int r = 0; r < 4; r++) {
                float v = acc[ct][r];
                ss[r] += v * avs;
                sd[r] += v * avd;
                int row = rbase + r;
                if (row < NN) h8[(size_t)row * 512 + colg] = f2fp8(v);
            }
        }
#pragma unroll
        for (int r = 0; r < 4; r++) {
            float a_ = ss[r], b_ = sd[r];
#pragma unroll
            for (int o = 1; o < 16; o <<= 1) {
                a_ += __shfl_xor(a_, o);
                b_ += __shfl_xor(b_, o);
            }
            int row = rbase + r;
            if (l16 == 0 && row < NN) {
                s1s[row * 8 + hh] = a_;
                s1d[row * 8 + hh] = b_;
            }
        }
    }
}

// ===== pass B standalone: padded local CSR build (391 blocks x 512) =====
__global__ __launch_bounds__(512) void passb_k(const int* __restrict__ bucket_cnt,
                                               const uint* __restrict__ staging,
                                               ushort* __restrict__ csru,
                                               int* __restrict__ rowptr) {
    __shared__ int hist2w[1024];   // [8][128] per-wave histogram
    __shared__ int cur2w[1024];    // [8][128] per-wave cursor
    __shared__ int wbase[1024];    // [8][128] per-wave base within node segment
    __shared__ int excl2[128];     // per-node exclusive scan
    __shared__ int wsum2[8];
    __shared__ int sbs;
    const int tid = threadIdx.x;
    const int b = blockIdx.x;
    const int cnt = bucket_cnt[b];
    const uint* sg = staging + (size_t)b * CAP;
    const int wv = tid >> 6;
    for (int i = tid; i < 2048; i += 512) {
        if (i < 1024) hist2w[i] = 0; else cur2w[i - 1024] = 0;
    }
    // wave 0: exclusive prefix of bucket_cnt up to bucket b (391 L2-hit reads)
    if (tid < 64) {
        int c[7]; int s0 = 0;
#pragma unroll
        for (int i = 0; i < 7; i++) {
            int bi = tid * 7 + i;
            c[i] = (bi < BUCKETS) ? bucket_cnt[bi] : 0;
            s0 += c[i];
        }
        int sc = s0;
#pragma unroll
        for (int o = 1; o < 64; o <<= 1) {
            int u = __shfl_up(sc, o);
            if (tid >= o) sc += u;
        }
        int run = sc - s0;   // exclusive prefix at this lane's first bucket
        if (tid == b / 7) {
            int part = run;
            for (int i = 0; i < b % 7; i++) part += c[i];
            sbs = part;
        }
    }
    if (b == 0 && tid == 0) rowptr[NN] = NE;
    __syncthreads();
    const int sbase = sbs;
    for (int e = tid; e < cnt; e += 512)
        atomicAdd(&hist2w[wv * 128 + ((sg[e] >> 16) & 127)], 1);
    __syncthreads();
    int v = 0;
    if (tid < 128) {
        int run = 0;
#pragma unroll
        for (int w = 0; w < 8; w++) {
            wbase[w * 128 + tid] = run;
            run += hist2w[w * 128 + tid];
        }
        v = run;                     // node total
    }
    int tot;
    int ex = scan512x(v, tid, wsum2, &tot);
    if (tid < 128) {
        excl2[tid] = ex;
        int n = b * 128 + tid;
        if (n < NN) rowptr[n] = sbase + ex;
    }
    __syncthreads();
    for (int e = tid; e < cnt; e += 512) {
        uint u = sg[e];
        int sl = (u >> 16) & 127;
        int pos = excl2[sl] + wbase[wv * 128 + sl] + atomicAdd(&cur2w[wv * 128 + sl], 1);
        csru[sbase + pos] = (ushort)(u & 0xFFFF);
    }
}

// ===== fused layer-1 aggregation (fp8 gather, one-ahead index prefetch) + GEMM2 + scores =====
// n_base: launched twice over half the node range each (keeps top-5 cutoff low; independent).
__global__ __launch_bounds__(256) void agg1f_k(const int n_base,
                                               const int* __restrict__ rowptr,
                                               const ushort* __restrict__ csru,
                                               const float* __restrict__ s1s,
                                               const float* __restrict__ s1d,
                                               const uint2* __restrict__ hb8,
                                               const ushort* __restrict__ W2tb,
                                               const float* __restrict__ a2,
                                               ushort* __restrict__ h2b,
                                               float* __restrict__ s2s,
                                               float* __restrict__ s2d) {
    __shared__ ushort Ash[16 * 512];
    unsigned char* ashb = (unsigned char*)Ash;
    const int tid = threadIdx.x;
    const int wv = tid >> 6, lane = tid & 63;
    const int n0 = n_base + blockIdx.x * 4;
    const int n = n0 + wv;              // NN % 4 == 0
    const int head8 = lane >> 3;
    const int hb = head8 << 3;
    const int esub = lane & 7;
    const int beg = rowptr[n];
    const int deg = rowptr[n + 1] - beg;
    const float ssrc = s1s[n * 8 + head8];
    floatx2 acc[4] = {};
    float rsum = 0.f;

    const int G = (deg + 7) >> 3;       // clamped groups; last group zero-weights invalid lanes
    const int dm1 = deg - 1;
    if (G > 0) {
        int dA = csru[beg + min(esub, dm1)];
        float tw = s1d[dA * 8 + head8];
        for (int g = 0; g < G; g++) {
            // gathers for the CURRENT group issue immediately (dA already in regs)
            uint2 v[8];
#pragma unroll
            for (int j = 0; j < 8; j++) {
                int dj = __shfl(dA, j);
                v[j] = hb8[(uint)dj * 64 + lane];
            }
            // one-ahead prefetch of next group's index + dst-score (clamped, ~4 VGPRs)
            int dAn = csru[beg + min(g * 8 + 8 + esub, dm1)];
            float twn = s1d[dAn * 8 + head8];
            float w = (g * 8 + esub <= dm1) ? edge_w(ssrc + tw) : 0.f;
            rsum += w;
#pragma unroll
            for (int j = 0; j < 8; j++) {
                float wj = __shfl(w, hb + j);
                floatx2 w2 = (floatx2){wj, wj};
                acc[0] += w2 * __builtin_amdgcn_cvt_pk_f32_fp8(v[j].x, false);
                acc[1] += w2 * __builtin_amdgcn_cvt_pk_f32_fp8(v[j].x, true);
                acc[2] += w2 * __builtin_amdgcn_cvt_pk_f32_fp8(v[j].y, false);
                acc[3] += w2 * __builtin_amdgcn_cvt_pk_f32_fp8(v[j].y, true);
            }
            dA = dAn;
            tw = twn;
        }
    }

    rsum += __shfl_xor(rsum, 1);
    rsum += __shfl_xor(rsum, 2);
    rsum += __shfl_xor(rsum, 4);
    float inv = 1.0f / rsum;
    uint4 o;
    o.x = packbf2(elu_f(acc[0][0] * inv), elu_f(acc[0][1] * inv));
    o.y = packbf2(elu_f(acc[1][0] * inv), elu_f(acc[1][1] * inv));
    o.z = packbf2(elu_f(acc[2][0] * inv), elu_f(acc[2][1] * inv));
    o.w = packbf2(elu_f(acc[3][0] * inv), elu_f(acc[3][1] * inv));
    // XOR-swizzled store: col16 ^ (row<<4) breaks stride-1024 bank aliasing for GEMM2 reads
    *(uint4*)(ashb + wv * 1024 + ((lane * 16) ^ (wv << 4))) = o;
    __syncthreads();

    if (wv == 0) {
        const int l16 = lane & 15, q = lane >> 4;
        floatx4 c2 = (floatx4){0.f, 0.f, 0.f, 0.f};
#pragma unroll
        for (int s = 0; s < 16; s++) {
            short8 af = *(const short8*)(ashb + l16 * 1024 +
                                         ((s * 64 + q * 16) ^ ((l16 & 7) << 4)));
            short8 bf = *(const short8*)(W2tb + l16 * 512 + s * 32 + q * 8);
            c2 = __builtin_amdgcn_mfma_f32_16x16x32_bf16(af, bf, c2, 0, 0, 0);
        }
        if (q == 0) {
#pragma unroll
            for (int r = 0; r < 4; r++) h2b[(size_t)(n0 + r) * 16 + l16] = f2bf(c2[r]);
        }
#pragma unroll
        for (int r = 0; r < 4; r++) {
            float ssv = c2[r] * a2[l16];
            float sdv = c2[r] * a2[16 + l16];
#pragma unroll
            for (int oo = 1; oo < 16; oo <<= 1) {
                ssv += __shfl_xor(ssv, oo);
                sdv += __shfl_xor(sdv, oo);
            }
            if (lane == 0) { s2s[n0 + r] = ssv; s2d[n0 + r] = sdv; }
        }
    }
}

// ===== layer-2 aggregation (bf16 h2, 8-deep ILP) + fused log_softmax =====
__global__ __launch_bounds__(256) void agg2_k(const int* __restrict__ rowptr,
                                              const ushort* __restrict__ csru,
                                              const float* __restrict__ s2s,
                                              const float* __restrict__ s2d,
                                              const ushort* __restrict__ h2b,
                                              float* __restrict__ out) {
    const int n = (blockIdx.x * 256 + threadIdx.x) >> 6;
    const int lane = threadIdx.x & 63;
    if (n >= NN) return;
    const int beg = rowptr[n], end = rowptr[n + 1];
    const float sn = s2s[n];
    const int sub = lane >> 4, f = lane & 15;
    float acc = 0.f, rsum = 0.f;
    int e = beg + sub;
    for (; e + 28 < end; e += 32) {          // 8 edges in flight per subgroup
        int d0 = csru[e], d1 = csru[e + 4], d2 = csru[e + 8], d3 = csru[e + 12];
        int d4 = csru[e + 16], d5 = csru[e + 20], d6 = csru[e + 24], d7 = csru[e + 28];
        float t0 = s2d[d0], t1 = s2d[d1], t2 = s2d[d2], t3 = s2d[d3];
        float t4 = s2d[d4], t5 = s2d[d5], t6 = s2d[d6], t7 = s2d[d7];
        float g0 = bf2f(h2b[(uint)d0 * 16 + f]), g1 = bf2f(h2b[(uint)d1 * 16 + f]);
        float g2 = bf2f(h2b[(uint)d2 * 16 + f]), g3 = bf2f(h2b[(uint)d3 * 16 + f]);
        float g4 = bf2f(h2b[(uint)d4 * 16 + f]), g5 = bf2f(h2b[(uint)d5 * 16 + f]);
        float g6 = bf2f(h2b[(uint)d6 * 16 + f]), g7 = bf2f(h2b[(uint)d7 * 16 + f]);
        float w0 = edge_w(sn + t0), w1 = edge_w(sn + t1);
        float w2 = edge_w(sn + t2), w3 = edge_w(sn + t3);
        float w4 = edge_w(sn + t4), w5 = edge_w(sn + t5);
        float w6 = edge_w(sn + t6), w7 = edge_w(sn + t7);
        acc += w0 * g0 + w1 * g1 + w2 * g2 + w3 * g3;
        acc += w4 * g4 + w5 * g5 + w6 * g6 + w7 * g7;
        rsum += w0 + w1 + w2 + w3 + w4 + w5 + w6 + w7;
    }
    for (; e + 12 < end; e += 16) {          // 4-deep remainder
        int d0 = csru[e], d1 = csru[e + 4], d2 = csru[e + 8], d3 = csru[e + 12];
        float t0 = s2d[d0], t1 = s2d[d1], t2 = s2d[d2], t3 = s2d[d3];
        float g0 = bf2f(h2b[(uint)d0 * 16 + f]), g1 = bf2f(h2b[(uint)d1 * 16 + f]);
        float g2 = bf2f(h2b[(uint)d2 * 16 + f]), g3 = bf2f(h2b[(uint)d3 * 16 + f]);
        float w0 = edge_w(sn + t0), w1 = edge_w(sn + t1);
        float w2 = edge_w(sn + t2), w3 = edge_w(sn + t3);
        acc += w0 * g0 + w1 * g1 + w2 * g2 + w3 * g3;
        rsum += w0 + w1 + w2 + w3;
    }
    for (; e < end; e += 4) {
        int d0 = csru[e];
        float w0 = edge_w(sn + s2d[d0]);
        acc += w0 * bf2f(h2b[(uint)d0 * 16 + f]);
        rsum += w0;
    }
    acc += __shfl_down(acc, 32);
    acc += __shfl_down(acc, 16);
    rsum += __shfl_down(rsum, 32);
    rsum += __shfl_down(rsum, 16);
    if (lane < 16) {
        float v = elu_f(acc / rsum);
        float m = v;
#pragma unroll
        for (int o = 8; o > 0; o >>= 1) m = fmaxf(m, __shfl_xor(m, o));
        float ex = __expf(v - m), s = ex;
#pragma unroll
        for (int o = 8; o > 0; o >>= 1) s += __shfl_xor(s, o);
        out[(size_t)n * 16 + f] = v - (__logf(s) + m);
    }
}

extern "C" void kernel_launch(void* const* d_in, const int* in_sizes, int n_in,
                              void* d_out, int out_size, void* d_ws, size_t ws_size,
                              hipStream_t stream) {
    const float* x  = (const float*)d_in[0];
    const int*   ei = (const int*)d_in[1];
    const float* W1 = (const float*)d_in[2];
    const float* a1 = (const float*)d_in[3];
    const float* W2 = (const float*)d_in[4];
    const float* a2 = (const float*)d_in[5];
    float* out = (float*)d_out;

    unsigned char* h8  = (unsigned char*)d_ws;              // 50048*512 = 25.62 MB
    unsigned char* Wt8 = h8 + (size_t)NROW_PAD * 512;       // 256 KB
    ushort* W2tb  = (ushort*)(Wt8 + 512 * 512);             // 16 KB
    float* s1s    = (float*)(W2tb + 8192);                  // 1.6 MB
    float* s1d    = s1s + (size_t)NN * H1;                  // 1.6 MB
    int* rowptr   = (int*)(s1d + (size_t)NN * H1);          // NN+1 (padded to 50056)
    int* bucket_cnt   = rowptr + 50056;                     // 512 ints
    int* bucket_start = bucket_cnt + 512;                   // 512 ints (unused, kept for layout)
    ushort* csru  = (ushort*)(bucket_start + 512);          // 3.2 MB
    ushort* h2b   = csru + NE;                              // 1.6 MB
    float* s2s    = (float*)(h2b + (size_t)NN * 16);        // 200 KB
    float* s2d    = s2s + NN;                               // 200 KB
    uint* staging = (uint*)(s2d + NN);                      // 391*6144*4 = 9.6 MB

    hipMemsetAsync(bucket_cnt, 0, 512 * sizeof(int), stream);

    prep_w_k<<<PACK_BLKS + PACK2_BLKS, 256, 0, stream>>>(W1, Wt8, W2, W2tb);
    passa_gemm1_k<<<PASSA_BLKS + GEMMB, 512, 0, stream>>>(ei, bucket_cnt, staging,
                                                          x, Wt8, a1, h8, s1s, s1d);
    passb_k<<<PASSB_BLKS, 512, 0, stream>>>(bucket_cnt, staging, csru, rowptr);
    agg1f_k<<<NN / 8, 256, 0, stream>>>(0, rowptr, csru, s1s, s1d,
                                        (const uint2*)h8, W2tb, a2, h2b, s2s, s2d);
    agg1f_k<<<NN / 8, 256, 0, stream>>>(NN / 2, rowptr, csru, s1s, s1d,
                                        (const uint2*)h8, W2tb, a2, h2b, s2s, s2d);
    agg2_k<<<(NN + 3) / 4, 256, 0, stream>>>(rowptr, csru, s2s, s2d, h2b, out);
}

// Round 16
// 386.112 us; speedup vs baseline: 1.0402x; 1.0308x over previous
//
#include <hip/hip_runtime.h>

#define NN 50000
#define NE 1600000
#define NFEAT 512
#define NHID 64
#define H1 8
#define NCLASS 16
#define ALPHA 0.2f

// bucketed CSR build: bucket = src >> 7 (128 nodes/bucket)
#define BUCKETS 391
#define CAP 6144              // staging slots per bucket
#define EPB 4096              // edges per pass-A block
#define PASSA_BLKS 391
#define PASSB_BLKS 391
#define PACK_BLKS 1024
#define PACK2_BLKS 32
#define GEMMB 391             // 391 row-blocks of 128, each does all 512 cols
#define NROW_PAD 50048        // 391*128

typedef __attribute__((ext_vector_type(8))) short short8;
typedef __attribute__((ext_vector_type(4))) float floatx4;
typedef __attribute__((ext_vector_type(2))) float floatx2;
typedef __attribute__((ext_vector_type(2))) long longx2;

__device__ __forceinline__ float elu_f(float x) { return x > 0.0f ? x : __expf(x) - 1.0f; }
__device__ __forceinline__ float edge_w(float logit) {
    return __expf(-fmaxf(logit, ALPHA * logit));   // exp(-leaky_relu)
}
__device__ __forceinline__ ushort f2bf(float f) {
    uint u = __float_as_uint(f);
    return (ushort)((u + 0x7FFFu + ((u >> 16) & 1)) >> 16);   // RNE
}
__device__ __forceinline__ uint packbf2(float lo, float hi) {
    return (uint)f2bf(lo) | ((uint)f2bf(hi) << 16);
}
__device__ __forceinline__ float bf2f(ushort v) { return __uint_as_float((uint)v << 16); }
__device__ __forceinline__ unsigned char f2fp8(float v) {
    return (unsigned char)(__builtin_amdgcn_cvt_pk_fp8_f32(v, v, 0, false) & 0xFF);
}
__device__ __forceinline__ uint pack4fp8(float a, float b, float c, float d) {
    uint u = __builtin_amdgcn_cvt_pk_fp8_f32(a, b, 0, false);
    return __builtin_amdgcn_cvt_pk_fp8_f32(c, d, u, true);
}

#define GLD16(g, l)                                                              \
    __builtin_amdgcn_global_load_lds(                                            \
        (const __attribute__((address_space(1))) unsigned int*)(g),              \
        (__attribute__((address_space(3))) unsigned int*)(l), 16, 0, 0)

// 512-thread block-wide exclusive scan (one value per thread); *tot gets the sum.
__device__ __forceinline__ int scan512x(int v, int tid, int* wsum, int* tot) {
    int s = v;
#pragma unroll
    for (int o = 1; o < 64; o <<= 1) {
        int u = __shfl_up(s, o);
        if ((tid & 63) >= o) s += u;
    }
    __syncthreads();
    if ((tid & 63) == 63) wsum[tid >> 6] = s;
    __syncthreads();
    int off = 0, t = 0;
#pragma unroll
    for (int i = 0; i < 8; i++) {
        int x = wsum[i];
        if (i < (tid >> 6)) off += x;
        t += x;
    }
    *tot = t;
    return s - v + off;
}

// ------- phase 0: pack W1 fp8 (swizzled) | pack W2^T bf16 | zero bucket_cnt -------
__global__ __launch_bounds__(256) void prep_w_k(const float* __restrict__ W1,
                                                unsigned char* __restrict__ Wt8,
                                                const float* __restrict__ W2,
                                                ushort* __restrict__ W2tb,
                                                int* __restrict__ bucket_cnt) {
    int b = blockIdx.x;
    if (b < PACK_BLKS) {
        int i = b * 256 + threadIdx.x;   // OUTPUT index = c*512 + o
        int c = i >> 9, o = i & 511;
        int c6 = o >> 6, qhi = (o >> 4) & 3, kb = (o >> 3) & 1, bb = o & 7;
        int quad = qhi ^ ((c >> 1) & 3);
        int k = c6 * 64 + kb * 32 + quad * 8 + bb;
        Wt8[i] = f2fp8(W1[((c >> 6) * 512 + k) * 64 + (c & 63)]);
        return;
    }
    if (b < PACK_BLKS + PACK2_BLKS) {
        int i = (b - PACK_BLKS) * 256 + threadIdx.x;   // i = c*512 + f
        int c = i >> 9, f = i & 511;
        W2tb[i] = f2bf(W2[f * 16 + c]);
        return;
    }
    // last block: zero bucket_cnt (replaces hipMemsetAsync dispatch)
    bucket_cnt[threadIdx.x] = 0;
    bucket_cnt[threadIdx.x + 256] = 0;
}

// ===== merged: pass A bucket sort (blocks 0..390) | GEMM1 fp8 MFMA (blocks 391..781) =====
// pass A co-resides with the latency-bound GEMM blocks and largely hides under them.
__global__ __launch_bounds__(512) void passa_gemm1_k(const int* __restrict__ ei,
                                                     int* __restrict__ bucket_cnt,
                                                     uint* __restrict__ staging,
                                                     const float* __restrict__ x,
                                                     const unsigned char* __restrict__ Wt8,
                                                     const float* __restrict__ a1,
                                                     unsigned char* __restrict__ h8,
                                                     float* __restrict__ s1s,
                                                     float* __restrict__ s1d) {
    __shared__ unsigned char shmem[32768];   // GEMM: Bs 32 KB; pass-A: ~21 KB arrays
    const int tid = threadIdx.x;

    if (blockIdx.x < PASSA_BLKS) {
        // ---- pass A (512 threads): LDS counting-sort 4096 edges by bucket ----
        int* histA = (int*)shmem;            // 391 (padded 400)
        int* exclA = histA + 400;            // 391
        int* baseA = exclA + 400;            // 391
        int* wsumA = baseA + 400;            // 8
        uint* ebuf = (uint*)(wsumA + 8);     // 4096
        const int blk = blockIdx.x;
        const int e0 = blk * EPB;
        const int cntb = min(EPB, NE - e0);
        for (int i = tid; i < BUCKETS; i += 512) histA[i] = 0;
        __syncthreads();
        int br[8]; uint pay[8];
#pragma unroll
        for (int i = 0; i < 8; i++) {
            int e = e0 + i * 512 + tid;
            br[i] = -1;
            if (e < NE) {
                int s = ei[e], d = ei[NE + e];
                int bu = s >> 7;
                pay[i] = ((uint)bu << 23) | ((uint)(s & 127) << 16) | (uint)d;  // 9b|7b|16b
                br[i] = (bu << 12) | atomicAdd(&histA[bu], 1);                  // rank < 4096
            }
        }
        __syncthreads();
        int v = (tid < BUCKETS) ? histA[tid] : 0;
        int tot;
        int ex = scan512x(v, tid, wsumA, &tot);
        if (tid < BUCKETS) exclA[tid] = ex;
        __syncthreads();
        for (int i = tid; i < BUCKETS; i += 512) {
            int c = histA[i];
            if (c > 0) baseA[i] = atomicAdd(&bucket_cnt[i], c);
        }
#pragma unroll
        for (int i = 0; i < 8; i++)
            if (br[i] >= 0) ebuf[exclA[br[i] >> 12] + (br[i] & 4095)] = pay[i];
        __syncthreads();
        for (int j = tid; j < cntb; j += 512) {
            uint u = ebuf[j];
            int bu = u >> 23;
            int pos = baseA[bu] + (j - exclA[bu]);
            staging[(size_t)bu * CAP + pos] = u;
        }
        return;
    }

    // ------------------ GEMM1 ------------------
    unsigned char* Bs = shmem;              // 512 x 64 = 32 KB
    const int gb = blockIdx.x - PASSA_BLKS;
    const int row0 = gb * 128;
    const int wv = tid >> 6, lane = tid & 63;
    const int l16 = lane & 15, quad = lane >> 4;
    const int qoff = ((quad ^ ((l16 >> 1) & 3)) << 4);   // swizzled 16-B slot (B reads)
    const int mA = wv * 16 + (lane >> 2);
    const int offA = (lane & 3) * 16;
    const unsigned char* gB0 = Wt8 + (size_t)(0 * 128 + mA) * 512 + offA;
    const unsigned char* gB1 = Wt8 + (size_t)(1 * 128 + mA) * 512 + offA;
    const unsigned char* gB2 = Wt8 + (size_t)(2 * 128 + mA) * 512 + offA;
    const unsigned char* gB3 = Wt8 + (size_t)(3 * 128 + mA) * 512 + offA;
    const int arow = row0 + wv * 16 + l16;               // this lane's A row
    const int arowc = min(arow, NN - 1);                 // clamp (pad rows discarded)
    const float* xA = x + (size_t)arowc * 512 + quad * 8;

    floatx4 acc[32];
#pragma unroll
    for (int ct = 0; ct < 32; ct++) acc[ct] = (floatx4){0.f, 0.f, 0.f, 0.f};

    for (int t = 0; t < 8; t++) {
        const int k0 = t * 64;
        GLD16(gB0 + k0, Bs + wv * 1024);
        GLD16(gB1 + k0, Bs + 8192 + wv * 1024);
        GLD16(gB2 + k0, Bs + 16384 + wv * 1024);
        GLD16(gB3 + k0, Bs + 24576 + wv * 1024);
        // A fragment: k = k0 + quad*8 + b (kb=0) and k0 + 32 + quad*8 + b (kb=1)
        float4 f0 = *(const float4*)(xA + k0);
        float4 f1 = *(const float4*)(xA + k0 + 4);
        float4 f2 = *(const float4*)(xA + k0 + 32);
        float4 f3 = *(const float4*)(xA + k0 + 36);
        uint u0 = pack4fp8(f0.x, f0.y, f0.z, f0.w);
        uint u1 = pack4fp8(f1.x, f1.y, f1.z, f1.w);
        uint u2 = pack4fp8(f2.x, f2.y, f2.z, f2.w);
        uint u3 = pack4fp8(f3.x, f3.y, f3.z, f3.w);
        long ax = (long)(((unsigned long)u1 << 32) | u0);
        long ay = (long)(((unsigned long)u3 << 32) | u2);
        __syncthreads();                 // B tile visible (drains GLD16 too)
        const unsigned char* bp = Bs + l16 * 64 + qoff;
#pragma unroll
        for (int ct = 0; ct < 32; ct++) {
            longx2 bv = *(const longx2*)(bp + ct * 1024);
            acc[ct] = __builtin_amdgcn_mfma_f32_16x16x32_fp8_fp8(ax, bv.x, acc[ct], 0, 0, 0);
            acc[ct] = __builtin_amdgcn_mfma_f32_16x16x32_fp8_fp8(ay, bv.y, acc[ct], 0, 0, 0);
        }
        __syncthreads();                 // all reads done before next-tile overwrite
    }

    // epilogue: h8 write + a1 scores
    const int rbase = row0 + wv * 16 + quad * 4;
#pragma unroll
    for (int hh = 0; hh < 8; hh++) {
        float ss[4] = {0.f, 0.f, 0.f, 0.f}, sd[4] = {0.f, 0.f, 0.f, 0.f};
#pragma unroll
        for (int c4 = 0; c4 < 4; c4++) {
            int ct = hh * 4 + c4;
            int colg = ct * 16 + l16;
            float avs = a1[hh * 128 + c4 * 16 + l16];
            float avd = a1[hh * 128 + 64 + c4 * 16 + l16];
#pragma unroll
            for (int r = 0; r < 4; r++) {
                float v = acc[ct][r];
                ss[r] += v * avs;
                sd[r] += v * avd;
                int row = rbase + r;
                if (row < NN) h8[(size_t)row * 512 + colg] = f2fp8(v);
            }
        }
#pragma unroll
        for (int r = 0; r < 4; r++) {
            float a_ = ss[r], b_ = sd[r];
#pragma unroll
            for (int o = 1; o < 16; o <<= 1) {
                a_ += __shfl_xor(a_, o);
                b_ += __shfl_xor(b_, o);
            }
            int row = rbase + r;
            if (l16 == 0 && row < NN) {
                s1s[row * 8 + hh] = a_;
                s1d[row * 8 + hh] = b_;
            }
        }
    }
}

// ===== pass B standalone: padded local CSR build (391 blocks x 512) =====
__global__ __launch_bounds__(512) void passb_k(const int* __restrict__ bucket_cnt,
                                               const uint* __restrict__ staging,
                                               ushort* __restrict__ csru,
                                               int* __restrict__ rowptr) {
    __shared__ int hist2w[1024];   // [8][128] per-wave histogram
    __shared__ int cur2w[1024];    // [8][128] per-wave cursor
    __shared__ int wbase[1024];    // [8][128] per-wave base within node segment
    __shared__ int excl2[128];     // per-node exclusive scan
    __shared__ int wsum2[8];
    __shared__ int sbs;
    const int tid = threadIdx.x;
    const int b = blockIdx.x;
    const int cnt = bucket_cnt[b];
    const uint* sg = staging + (size_t)b * CAP;
    const int wv = tid >> 6;
    for (int i = tid; i < 2048; i += 512) {
        if (i < 1024) hist2w[i] = 0; else cur2w[i - 1024] = 0;
    }
    // wave 0: exclusive prefix of bucket_cnt up to bucket b (391 L2-hit reads)
    if (tid < 64) {
        int c[7]; int s0 = 0;
#pragma unroll
        for (int i = 0; i < 7; i++) {
            int bi = tid * 7 + i;
            c[i] = (bi < BUCKETS) ? bucket_cnt[bi] : 0;
            s0 += c[i];
        }
        int sc = s0;
#pragma unroll
        for (int o = 1; o < 64; o <<= 1) {
            int u = __shfl_up(sc, o);
            if (tid >= o) sc += u;
        }
        int run = sc - s0;   // exclusive prefix at this lane's first bucket
        if (tid == b / 7) {
            int part = run;
            for (int i = 0; i < b % 7; i++) part += c[i];
            sbs = part;
        }
    }
    if (b == 0 && tid == 0) rowptr[NN] = NE;
    __syncthreads();
    const int sbase = sbs;
    for (int e = tid; e < cnt; e += 512)
        atomicAdd(&hist2w[wv * 128 + ((sg[e] >> 16) & 127)], 1);
    __syncthreads();
    int v = 0;
    if (tid < 128) {
        int run = 0;
#pragma unroll
        for (int w = 0; w < 8; w++) {
            wbase[w * 128 + tid] = run;
            run += hist2w[w * 128 + tid];
        }
        v = run;                     // node total
    }
    int tot;
    int ex = scan512x(v, tid, wsum2, &tot);
    if (tid < 128) {
        excl2[tid] = ex;
        int n = b * 128 + tid;
        if (n < NN) rowptr[n] = sbase + ex;
    }
    __syncthreads();
    for (int e = tid; e < cnt; e += 512) {
        uint u = sg[e];
        int sl = (u >> 16) & 127;
        int pos = excl2[sl] + wbase[wv * 128 + sl] + atomicAdd(&cur2w[wv * 128 + sl], 1);
        csru[sbase + pos] = (ushort)(u & 0xFFFF);
    }
}

// ===== fused layer-1 aggregation (fp8 gather, one-ahead index prefetch) + GEMM2 + scores =====
__global__ __launch_bounds__(256) void agg1f_k(const int* __restrict__ rowptr,
                                               const ushort* __restrict__ csru,
                                               const float* __restrict__ s1s,
                                               const float* __restrict__ s1d,
                                               const uint2* __restrict__ hb8,
                                               const ushort* __restrict__ W2tb,
                                               const float* __restrict__ a2,
                                               ushort* __restrict__ h2b,
                                               float* __restrict__ s2s,
                                               float* __restrict__ s2d) {
    __shared__ ushort Ash[16 * 512];
    unsigned char* ashb = (unsigned char*)Ash;
    const int tid = threadIdx.x;
    const int wv = tid >> 6, lane = tid & 63;
    const int n0 = blockIdx.x * 4;
    const int n = n0 + wv;              // NN % 4 == 0
    const int head8 = lane >> 3;
    const int hb = head8 << 3;
    const int esub = lane & 7;
    const int beg = rowptr[n];
    const int deg = rowptr[n + 1] - beg;
    const float ssrc = s1s[n * 8 + head8];
    floatx2 acc[4] = {};
    float rsum = 0.f;

    const int G = (deg + 7) >> 3;       // clamped groups; last group zero-weights invalid lanes
    const int dm1 = deg - 1;
    if (G > 0) {
        int dA = csru[beg + min(esub, dm1)];
        float tw = s1d[dA * 8 + head8];
        for (int g = 0; g < G; g++) {
            // gathers for the CURRENT group issue immediately (dA already in regs)
            uint2 v[8];
#pragma unroll
            for (int j = 0; j < 8; j++) {
                int dj = __shfl(dA, j);
                v[j] = hb8[(uint)dj * 64 + lane];
            }
            // one-ahead prefetch of next group's index + dst-score (clamped, ~4 VGPRs)
            int dAn = csru[beg + min(g * 8 + 8 + esub, dm1)];
            float twn = s1d[dAn * 8 + head8];
            float w = (g * 8 + esub <= dm1) ? edge_w(ssrc + tw) : 0.f;
            rsum += w;
#pragma unroll
            for (int j = 0; j < 8; j++) {
                float wj = __shfl(w, hb + j);
                floatx2 w2 = (floatx2){wj, wj};
                acc[0] += w2 * __builtin_amdgcn_cvt_pk_f32_fp8(v[j].x, false);
                acc[1] += w2 * __builtin_amdgcn_cvt_pk_f32_fp8(v[j].x, true);
                acc[2] += w2 * __builtin_amdgcn_cvt_pk_f32_fp8(v[j].y, false);
                acc[3] += w2 * __builtin_amdgcn_cvt_pk_f32_fp8(v[j].y, true);
            }
            dA = dAn;
            tw = twn;
        }
    }

    rsum += __shfl_xor(rsum, 1);
    rsum += __shfl_xor(rsum, 2);
    rsum += __shfl_xor(rsum, 4);
    float inv = 1.0f / rsum;
    uint4 o;
    o.x = packbf2(elu_f(acc[0][0] * inv), elu_f(acc[0][1] * inv));
    o.y = packbf2(elu_f(acc[1][0] * inv), elu_f(acc[1][1] * inv));
    o.z = packbf2(elu_f(acc[2][0] * inv), elu_f(acc[2][1] * inv));
    o.w = packbf2(elu_f(acc[3][0] * inv), elu_f(acc[3][1] * inv));
    // XOR-swizzled store: col16 ^ (row<<4) breaks stride-1024 bank aliasing for GEMM2 reads
    *(uint4*)(ashb + wv * 1024 + ((lane * 16) ^ (wv << 4))) = o;
    __syncthreads();

    if (wv == 0) {
        const int l16 = lane & 15, q = lane >> 4;
        floatx4 c2 = (floatx4){0.f, 0.f, 0.f, 0.f};
#pragma unroll
        for (int s = 0; s < 16; s++) {
            short8 af = *(const short8*)(ashb + l16 * 1024 +
                                         ((s * 64 + q * 16) ^ ((l16 & 7) << 4)));
            short8 bf = *(const short8*)(W2tb + l16 * 512 + s * 32 + q * 8);
            c2 = __builtin_amdgcn_mfma_f32_16x16x32_bf16(af, bf, c2, 0, 0, 0);
        }
        if (q == 0) {
#pragma unroll
            for (int r = 0; r < 4; r++) h2b[(size_t)(n0 + r) * 16 + l16] = f2bf(c2[r]);
        }
#pragma unroll
        for (int r = 0; r < 4; r++) {
            float ssv = c2[r] * a2[l16];
            float sdv = c2[r] * a2[16 + l16];
#pragma unroll
            for (int oo = 1; oo < 16; oo <<= 1) {
                ssv += __shfl_xor(ssv, oo);
                sdv += __shfl_xor(sdv, oo);
            }
            if (lane == 0) { s2s[n0 + r] = ssv; s2d[n0 + r] = sdv; }
        }
    }
}

// ===== layer-2 aggregation (bf16 h2, 8-deep ILP) + fused log_softmax =====
__global__ __launch_bounds__(256) void agg2_k(const int* __restrict__ rowptr,
                                              const ushort* __restrict__ csru,
                                              const float* __restrict__ s2s,
                                              const float* __restrict__ s2d,
                                              const ushort* __restrict__ h2b,
                                              float* __restrict__ out) {
    const int n = (blockIdx.x * 256 + threadIdx.x) >> 6;
    const int lane = threadIdx.x & 63;
    if (n >= NN) return;
    const int beg = rowptr[n], end = rowptr[n + 1];
    const float sn = s2s[n];
    const int sub = lane >> 4, f = lane & 15;
    float acc = 0.f, rsum = 0.f;
    int e = beg + sub;
    for (; e + 28 < end; e += 32) {          // 8 edges in flight per subgroup
        int d0 = csru[e], d1 = csru[e + 4], d2 = csru[e + 8], d3 = csru[e + 12];
        int d4 = csru[e + 16], d5 = csru[e + 20], d6 = csru[e + 24], d7 = csru[e + 28];
        float t0 = s2d[d0], t1 = s2d[d1], t2 = s2d[d2], t3 = s2d[d3];
        float t4 = s2d[d4], t5 = s2d[d5], t6 = s2d[d6], t7 = s2d[d7];
        float g0 = bf2f(h2b[(uint)d0 * 16 + f]), g1 = bf2f(h2b[(uint)d1 * 16 + f]);
        float g2 = bf2f(h2b[(uint)d2 * 16 + f]), g3 = bf2f(h2b[(uint)d3 * 16 + f]);
        float g4 = bf2f(h2b[(uint)d4 * 16 + f]), g5 = bf2f(h2b[(uint)d5 * 16 + f]);
        float g6 = bf2f(h2b[(uint)d6 * 16 + f]), g7 = bf2f(h2b[(uint)d7 * 16 + f]);
        float w0 = edge_w(sn + t0), w1 = edge_w(sn + t1);
        float w2 = edge_w(sn + t2), w3 = edge_w(sn + t3);
        float w4 = edge_w(sn + t4), w5 = edge_w(sn + t5);
        float w6 = edge_w(sn + t6), w7 = edge_w(sn + t7);
        acc += w0 * g0 + w1 * g1 + w2 * g2 + w3 * g3;
        acc += w4 * g4 + w5 * g5 + w6 * g6 + w7 * g7;
        rsum += w0 + w1 + w2 + w3 + w4 + w5 + w6 + w7;
    }
    for (; e + 12 < end; e += 16) {          // 4-deep remainder
        int d0 = csru[e], d1 = csru[e + 4], d2 = csru[e + 8], d3 = csru[e + 12];
        float t0 = s2d[d0], t1 = s2d[d1], t2 = s2d[d2], t3 = s2d[d3];
        float g0 = bf2f(h2b[(uint)d0 * 16 + f]), g1 = bf2f(h2b[(uint)d1 * 16 + f]);
        float g2 = bf2f(h2b[(uint)d2 * 16 + f]), g3 = bf2f(h2b[(uint)d3 * 16 + f]);
        float w0 = edge_w(sn + t0), w1 = edge_w(sn + t1);
        float w2 = edge_w(sn + t2), w3 = edge_w(sn + t3);
        acc += w0 * g0 + w1 * g1 + w2 * g2 + w3 * g3;
        rsum += w0 + w1 + w2 + w3;
    }
    for (; e < end; e += 4) {
        int d0 = csru[e];
        float w0 = edge_w(sn + s2d[d0]);
        acc += w0 * bf2f(h2b[(uint)d0 * 16 + f]);
        rsum += w0;
    }
    acc += __shfl_down(acc, 32);
    acc += __shfl_down(acc, 16);
    rsum += __shfl_down(rsum, 32);
    rsum += __shfl_down(rsum, 16);
    if (lane < 16) {
        float v = elu_f(acc / rsum);
        float m = v;
#pragma unroll
        for (int o = 8; o > 0; o >>= 1) m = fmaxf(m, __shfl_xor(m, o));
        float ex = __expf(v - m), s = ex;
#pragma unroll
        for (int o = 8; o > 0; o >>= 1) s += __shfl_xor(s, o);
        out[(size_t)n * 16 + f] = v - (__logf(s) + m);
    }
}

extern "C" void kernel_launch(void* const* d_in, const int* in_sizes, int n_in,
                              void* d_out, int out_size, void* d_ws, size_t ws_size,
                              hipStream_t stream) {
    const float* x  = (const float*)d_in[0];
    const int*   ei = (const int*)d_in[1];
    const float* W1 = (const float*)d_in[2];
    const float* a1 = (const float*)d_in[3];
    const float* W2 = (const float*)d_in[4];
    const float* a2 = (const float*)d_in[5];
    float* out = (float*)d_out;

    unsigned char* h8  = (unsigned char*)d_ws;              // 50048*512 = 25.62 MB
    unsigned char* Wt8 = h8 + (size_t)NROW_PAD * 512;       // 256 KB
    ushort* W2tb  = (ushort*)(Wt8 + 512 * 512);             // 16 KB
    float* s1s    = (float*)(W2tb + 8192);                  // 1.6 MB
    float* s1d    = s1s + (size_t)NN * H1;                  // 1.6 MB
    int* rowptr   = (int*)(s1d + (size_t)NN * H1);          // NN+1 (padded to 50056)
    int* bucket_cnt   = rowptr + 50056;                     // 512 ints
    int* bucket_start = bucket_cnt + 512;                   // 512 ints (unused, kept for layout)
    ushort* csru  = (ushort*)(bucket_start + 512);          // 3.2 MB
    ushort* h2b   = csru + NE;                              // 1.6 MB
    float* s2s    = (float*)(h2b + (size_t)NN * 16);        // 200 KB
    float* s2d    = s2s + NN;                               // 200 KB
    uint* staging = (uint*)(s2d + NN);                      // 391*6144*4 = 9.6 MB

    prep_w_k<<<PACK_BLKS + PACK2_BLKS + 1, 256, 0, stream>>>(W1, Wt8, W2, W2tb, bucket_cnt);
    passa_gemm1_k<<<PASSA_BLKS + GEMMB, 512, 0, stream>>>(ei, bucket_cnt, staging,
                                                          x, Wt8, a1, h8, s1s, s1d);
    passb_k<<<PASSB_BLKS, 512, 0, stream>>>(bucket_cnt, staging, csru, rowptr);
    agg1f_k<<<NN / 4, 256, 0, stream>>>(rowptr, csru, s1s, s1d,
                                        (const uint2*)h8, W2tb, a2, h2b, s2s, s2d);
    agg2_k<<<(NN + 3) / 4, 256, 0, stream>>>(rowptr, csru, s2s, s2d, h2b, out);
}